// Round 3
// baseline (607.728 us; speedup 1.0000x reference)
//
#include <hip/hip_runtime.h>
#include <math.h>

#define SQ 1024
#define DIM 1024
#define NH 16
#define HDIM 64

// ---------------- relative-position table: Rc[p][i], p = s - t + 1023 ----------------
__global__ __launch_bounds__(256) void relpos_kernel(float* __restrict__ Rc) {
  int gid = blockIdx.x * 256 + threadIdx.x;   // 0 .. 65535
  int p = gid >> 5;                           // 0 .. 2047 (row 2047 is padding)
  int f = gid & 31;                           // 0 .. 31
  float pos = (float)(p - (SQ - 1));
  float invf = expf(-0.28782313662425575f * (float)f);  // 10000^(-f/32)
  float ang = pos * invf;
  Rc[p * HDIM + 2 * f]     = sinf(ang);
  Rc[p * HDIM + 2 * f + 1] = cosf(ang);
}

// ---------------- fp32 GEMM: C(M,N) = A(M,K) @ B(N,K)^T, M=N=K=1024 ----------------
// MODE 0: C0 = acc
// MODE 1: C0 = acc + bias0[n], C1 = acc + bias1[n]   (q projection -> qu, qv)
// MODE 2: C0 = acc + bias0[n]                        (output projection + bo)
template<int MODE>
__global__ __launch_bounds__(256) void gemm_bt(
    const float* __restrict__ A, const float* __restrict__ B,
    float* __restrict__ C0, float* __restrict__ C1,
    const float* __restrict__ bias0, const float* __restrict__ bias1)
{
  constexpr int BK = 32, PADG = 34;           // k-major tiles, pad 34 -> 2-way max
  __shared__ float As[BK * PADG];
  __shared__ float Bs[BK * PADG];
  const int tid = threadIdx.x;
  const int bm = blockIdx.y * 32, bn = blockIdx.x * 32;
  const int ty = tid >> 4, tx = tid & 15;     // 2x2 micro-tile
  const int lr = tid >> 3, lc = (tid & 7) * 4;
  float acc00 = 0.f, acc01 = 0.f, acc10 = 0.f, acc11 = 0.f;

  for (int k0 = 0; k0 < DIM; k0 += BK) {
    float4 av = *(const float4*)&A[(bm + lr) * DIM + k0 + lc];
    float4 bv = *(const float4*)&B[(bn + lr) * DIM + k0 + lc];
    __syncthreads();
    As[(lc + 0) * PADG + lr] = av.x; As[(lc + 1) * PADG + lr] = av.y;
    As[(lc + 2) * PADG + lr] = av.z; As[(lc + 3) * PADG + lr] = av.w;
    Bs[(lc + 0) * PADG + lr] = bv.x; Bs[(lc + 1) * PADG + lr] = bv.y;
    Bs[(lc + 2) * PADG + lr] = bv.z; Bs[(lc + 3) * PADG + lr] = bv.w;
    __syncthreads();
    #pragma unroll
    for (int kk = 0; kk < BK; kk++) {
      float2 a = *(const float2*)&As[kk * PADG + 2 * ty];
      float2 b = *(const float2*)&Bs[kk * PADG + 2 * tx];
      acc00 += a.x * b.x; acc01 += a.x * b.y;
      acc10 += a.y * b.x; acc11 += a.y * b.y;
    }
  }

  const int r0 = bm + 2 * ty, c0 = bn + 2 * tx;
  if (MODE == 0) {
    *(float2*)&C0[r0 * DIM + c0]       = make_float2(acc00, acc01);
    *(float2*)&C0[(r0 + 1) * DIM + c0] = make_float2(acc10, acc11);
  } else if (MODE == 1) {
    float u0 = bias0[c0], u1 = bias0[c0 + 1];
    float v0 = bias1[c0], v1 = bias1[c0 + 1];
    *(float2*)&C0[r0 * DIM + c0]       = make_float2(acc00 + u0, acc01 + u1);
    *(float2*)&C0[(r0 + 1) * DIM + c0] = make_float2(acc10 + u0, acc11 + u1);
    *(float2*)&C1[r0 * DIM + c0]       = make_float2(acc00 + v0, acc01 + v1);
    *(float2*)&C1[(r0 + 1) * DIM + c0] = make_float2(acc10 + v0, acc11 + v1);
  } else {
    float u0 = bias0[c0], u1 = bias0[c0 + 1];
    *(float2*)&C0[r0 * DIM + c0]       = make_float2(acc00 + u0, acc01 + u1);
    *(float2*)&C0[(r0 + 1) * DIM + c0] = make_float2(acc10 + u0, acc11 + u1);
  }
}

// ---------------- fused flash-style attention ----------------
// logits[s,t] = 0.125 * ( qu[s]·k[t] + qv[s]·Rc[s-t+1023] ), online softmax, PV.
// Block: one head, 32 s-rows. 256 threads = 16 ty (row pairs) x 16 tx.
__device__ __forceinline__ float dot4(float4 a, float4 b) {
  return a.x * b.x + a.y * b.y + a.z * b.z + a.w * b.w;
}

#define ROWS 32
#define TT 32
#define PAD 68

__global__ __launch_bounds__(256) void attn_fused(
    const float* __restrict__ qu, const float* __restrict__ qv,
    const float* __restrict__ kkp, const float* __restrict__ vvp,
    const float* __restrict__ Rc, float* __restrict__ attout)
{
  __shared__ float qus[ROWS * PAD], qvs[ROWS * PAD];
  __shared__ float kt[TT * PAD], vt[TT * PAD];
  __shared__ float rt[64 * PAD];
  __shared__ float pt[ROWS * 33];

  const int tid  = threadIdx.x;
  const int h    = blockIdx.x >> 5;
  const int s0   = (blockIdx.x & 31) * ROWS;
  const int col0 = h * HDIM;

  // stage qu/qv rows (32 x 64 each)
  {
    const int r = tid >> 4, c4 = (tid & 15) * 4;
    #pragma unroll
    for (int rr = 0; rr < 2; rr++) {
      int row = r + rr * 16;
      *(float4*)&qus[row * PAD + c4] = *(const float4*)&qu[(s0 + row) * DIM + col0 + c4];
      *(float4*)&qvs[row * PAD + c4] = *(const float4*)&qv[(s0 + row) * DIM + col0 + c4];
    }
  }

  const int ty = tid >> 4, tx = tid & 15;
  const int sA = 2 * ty, sB = 2 * ty + 1;   // rows owned
  // cols owned: tx and tx+16
  float m0 = -1e30f, m1 = -1e30f, l0 = 0.f, l1 = 0.f;
  float O0[4] = {0.f, 0.f, 0.f, 0.f}, O1[4] = {0.f, 0.f, 0.f, 0.f};

  for (int t0 = 0; t0 < SQ; t0 += TT) {
    __syncthreads();   // protect kt/vt/rt/pt from previous iteration's readers
    {
      const int r = tid >> 4, c4 = (tid & 15) * 4;
      #pragma unroll
      for (int rr = 0; rr < 2; rr++) {
        int row = r + rr * 16;
        *(float4*)&kt[row * PAD + c4] = *(const float4*)&kkp[(t0 + row) * DIM + col0 + c4];
        *(float4*)&vt[row * PAD + c4] = *(const float4*)&vvp[(t0 + row) * DIM + col0 + c4];
      }
      const int p_base = s0 - t0 + SQ - 1 - 31;   // in [0, 1984]
      #pragma unroll
      for (int rr = 0; rr < 4; rr++) {
        int row = r + rr * 16;
        *(float4*)&rt[row * PAD + c4] = *(const float4*)&Rc[(p_base + row) * HDIM + c4];
      }
    }
    __syncthreads();

    // ---- logits: 2 rows x 2 cols per thread ----
    float aK00 = 0.f, aK01 = 0.f, aK10 = 0.f, aK11 = 0.f;
    float aR00 = 0.f, aR01 = 0.f, aR10 = 0.f, aR11 = 0.f;
    const int dA0 = sA - tx + 31;   // rt row for (sA, tx); in [0,62] over all cases
    #pragma unroll
    for (int i = 0; i < HDIM; i += 4) {
      float4 a0 = *(const float4*)&qus[sA * PAD + i];
      float4 a1 = *(const float4*)&qus[sB * PAD + i];
      float4 b0 = *(const float4*)&qvs[sA * PAD + i];
      float4 b1 = *(const float4*)&qvs[sB * PAD + i];
      float4 k0v = *(const float4*)&kt[tx * PAD + i];
      float4 k1v = *(const float4*)&kt[(tx + 16) * PAD + i];
      float4 r00 = *(const float4*)&rt[dA0 * PAD + i];
      float4 r01 = *(const float4*)&rt[(dA0 - 16) * PAD + i];
      float4 r10 = *(const float4*)&rt[(dA0 + 1) * PAD + i];
      float4 r11 = *(const float4*)&rt[(dA0 - 15) * PAD + i];
      aK00 += dot4(a0, k0v); aK01 += dot4(a0, k1v);
      aK10 += dot4(a1, k0v); aK11 += dot4(a1, k1v);
      aR00 += dot4(b0, r00); aR01 += dot4(b0, r01);
      aR10 += dot4(b1, r10); aR11 += dot4(b1, r11);
    }
    float lgA0 = 0.125f * (aK00 + aR00);
    float lgA1 = 0.125f * (aK01 + aR01);
    float lgB0 = 0.125f * (aK10 + aR10);
    float lgB1 = 0.125f * (aK11 + aR11);

    // ---- online softmax (row reduce over 16 tx lanes) ----
    float tmA = fmaxf(lgA0, lgA1), tmB = fmaxf(lgB0, lgB1);
    #pragma unroll
    for (int o = 1; o < 16; o <<= 1) {
      tmA = fmaxf(tmA, __shfl_xor(tmA, o, 16));
      tmB = fmaxf(tmB, __shfl_xor(tmB, o, 16));
    }
    float mnA = fmaxf(m0, tmA), mnB = fmaxf(m1, tmB);
    float fA = __expf(m0 - mnA), fB = __expf(m1 - mnB);
    float pA0 = __expf(lgA0 - mnA), pA1 = __expf(lgA1 - mnA);
    float pB0 = __expf(lgB0 - mnB), pB1 = __expf(lgB1 - mnB);
    pt[sA * 33 + tx] = pA0; pt[sA * 33 + tx + 16] = pA1;
    pt[sB * 33 + tx] = pB0; pt[sB * 33 + tx + 16] = pB1;
    float smA = pA0 + pA1, smB = pB0 + pB1;
    #pragma unroll
    for (int o = 1; o < 16; o <<= 1) {
      smA += __shfl_xor(smA, o, 16);
      smB += __shfl_xor(smB, o, 16);
    }
    l0 = l0 * fA + smA; l1 = l1 * fB + smB;
    m0 = mnA; m1 = mnB;
    #pragma unroll
    for (int c = 0; c < 4; c++) { O0[c] *= fA; O1[c] *= fB; }
    __syncthreads();   // pt visible to all lanes of the row

    // ---- PV: dims tx*4 .. tx*4+3 for both rows ----
    #pragma unroll
    for (int j = 0; j < TT; j++) {
      float pA = pt[sA * 33 + j];
      float pB = pt[sB * 33 + j];
      float4 v4 = *(const float4*)&vt[j * PAD + tx * 4];
      O0[0] += pA * v4.x; O0[1] += pA * v4.y; O0[2] += pA * v4.z; O0[3] += pA * v4.w;
      O1[0] += pB * v4.x; O1[1] += pB * v4.y; O1[2] += pB * v4.z; O1[3] += pB * v4.w;
    }
  }

  float i0 = 1.f / l0, i1 = 1.f / l1;
  float4 w0 = make_float4(O0[0] * i0, O0[1] * i0, O0[2] * i0, O0[3] * i0);
  float4 w1 = make_float4(O1[0] * i1, O1[1] * i1, O1[2] * i1, O1[3] * i1);
  *(float4*)&attout[(s0 + sA) * DIM + col0 + tx * 4] = w0;
  *(float4*)&attout[(s0 + sB) * DIM + col0 + tx * 4] = w1;
}

extern "C" void kernel_launch(void* const* d_in, const int* in_sizes, int n_in,
                              void* d_out, int out_size, void* d_ws, size_t ws_size,
                              hipStream_t stream) {
  const float* value = (const float*)d_in[0];
  const float* key   = (const float*)d_in[1];
  const float* query = (const float*)d_in[2];
  const float* Wq    = (const float*)d_in[3];
  const float* Wk    = (const float*)d_in[4];
  const float* Wv    = (const float*)d_in[5];
  const float* u     = (const float*)d_in[6];
  const float* v     = (const float*)d_in[7];
  const float* Wo    = (const float*)d_in[8];
  const float* bo    = (const float*)d_in[9];
  float* out = (float*)d_out;

  float* ws     = (float*)d_ws;
  float* qu     = ws;                      // 1M floats
  float* qv     = qu  + (1 << 20);
  float* kkp    = qv  + (1 << 20);
  float* vvp    = kkp + (1 << 20);
  float* attout = vvp + (1 << 20);
  float* Rc     = attout + (1 << 20);      // 2048 * 64 floats

  relpos_kernel<<<256, 256, 0, stream>>>(Rc);

  dim3 gg(32, 32);
  gemm_bt<1><<<gg, 256, 0, stream>>>(query, Wq, qu, qv, u, v);
  gemm_bt<0><<<gg, 256, 0, stream>>>(key,   Wk, kkp, nullptr, nullptr, nullptr);
  gemm_bt<0><<<gg, 256, 0, stream>>>(value, Wv, vvp, nullptr, nullptr, nullptr);

  attn_fused<<<NH * (SQ / ROWS), 256, 0, stream>>>(qu, qv, kkp, vvp, Rc, attout);

  gemm_bt<2><<<gg, 256, 0, stream>>>(attout, Wo, out, nullptr, bo, nullptr);
}

// Round 4
// 208.332 us; speedup vs baseline: 2.9171x; 2.9171x over previous
//
#include <hip/hip_runtime.h>
#include <math.h>

#define SQ 1024
#define DIM 1024
#define NH 16
#define HDIM 64

typedef short bf16x8 __attribute__((ext_vector_type(8)));
typedef float f32x4 __attribute__((ext_vector_type(4)));

__device__ __forceinline__ unsigned short f2bf(float x) {
  unsigned int u = __builtin_bit_cast(unsigned int, x);
  u += 0x7FFFu + ((u >> 16) & 1u);
  return (unsigned short)(u >> 16);
}

// ---------- relative-position table Rc[p][d], p = s-t+1023, bf16 ----------
__global__ __launch_bounds__(256) void relpos_kernel(unsigned short* __restrict__ Rc) {
  int gid = blockIdx.x * 256 + threadIdx.x;   // 65536 = 2048 p x 32 f
  int p = gid >> 5, f = gid & 31;
  float pos = (float)(p - (SQ - 1));
  float invf = expf(-0.28782313662425575f * (float)f);   // 10000^(-f/32)
  float ang = pos * invf;
  Rc[p * HDIM + 2 * f]     = f2bf(sinf(ang));
  Rc[p * HDIM + 2 * f + 1] = f2bf(cosf(ang));
}

// ---------- bf16 MFMA GEMM: C(1024,1024) = A @ B^T (+epilogue) ----------
// MODE 0 (Q): qu = bf16((acc+u[n])*0.125), qv = bf16((acc+v[n])*0.125)
// MODE 1 (K): kkp = bf16(acc)
// MODE 2 (V): vvpT[n][m] = bf16(acc)   (transposed store)
// MODE 3 (O): A is bf16; out_f32 = acc + bo[n]
template<int MODE>
__global__ __launch_bounds__(256) void gemm16(
    const void* __restrict__ Ap, const float* __restrict__ B,
    unsigned short* __restrict__ C16a, unsigned short* __restrict__ C16b,
    float* __restrict__ Cf,
    const float* __restrict__ bias0, const float* __restrict__ bias1)
{
  __shared__ short As[64 * 72];
  __shared__ short Bs[64 * 72];
  const int tid = threadIdx.x;
  const int bm = blockIdx.y * 64, bn = blockIdx.x * 64;
  const int w = tid >> 6, l = tid & 63, g = l >> 4, q = l & 15;
  const int wr = w >> 1, wc = w & 1;
  const int srow = tid >> 2, sc = (tid & 3) * 16;
  f32x4 acc[2][2] = {};

  for (int k0 = 0; k0 < DIM; k0 += 64) {
    __syncthreads();
    if (MODE == 3) {
      const unsigned short* A16 = (const unsigned short*)Ap;
      const uint4* src = (const uint4*)&A16[(bm + srow) * DIM + k0 + sc];
      *(uint4*)&As[srow * 72 + sc]     = src[0];
      *(uint4*)&As[srow * 72 + sc + 8] = src[1];
    } else {
      const float* Af = (const float*)Ap;
      const float4* src = (const float4*)&Af[(bm + srow) * DIM + k0 + sc];
      float4 a0 = src[0], a1 = src[1], a2 = src[2], a3 = src[3];
      uint4 w0, w1;
      w0.x = (unsigned)f2bf(a0.x) | ((unsigned)f2bf(a0.y) << 16);
      w0.y = (unsigned)f2bf(a0.z) | ((unsigned)f2bf(a0.w) << 16);
      w0.z = (unsigned)f2bf(a1.x) | ((unsigned)f2bf(a1.y) << 16);
      w0.w = (unsigned)f2bf(a1.z) | ((unsigned)f2bf(a1.w) << 16);
      w1.x = (unsigned)f2bf(a2.x) | ((unsigned)f2bf(a2.y) << 16);
      w1.y = (unsigned)f2bf(a2.z) | ((unsigned)f2bf(a2.w) << 16);
      w1.z = (unsigned)f2bf(a3.x) | ((unsigned)f2bf(a3.y) << 16);
      w1.w = (unsigned)f2bf(a3.z) | ((unsigned)f2bf(a3.w) << 16);
      *(uint4*)&As[srow * 72 + sc]     = w0;
      *(uint4*)&As[srow * 72 + sc + 8] = w1;
    }
    {
      const float4* src = (const float4*)&B[(bn + srow) * DIM + k0 + sc];
      float4 b0 = src[0], b1 = src[1], b2 = src[2], b3 = src[3];
      uint4 w0, w1;
      w0.x = (unsigned)f2bf(b0.x) | ((unsigned)f2bf(b0.y) << 16);
      w0.y = (unsigned)f2bf(b0.z) | ((unsigned)f2bf(b0.w) << 16);
      w0.z = (unsigned)f2bf(b1.x) | ((unsigned)f2bf(b1.y) << 16);
      w0.w = (unsigned)f2bf(b1.z) | ((unsigned)f2bf(b1.w) << 16);
      w1.x = (unsigned)f2bf(b2.x) | ((unsigned)f2bf(b2.y) << 16);
      w1.y = (unsigned)f2bf(b2.z) | ((unsigned)f2bf(b2.w) << 16);
      w1.z = (unsigned)f2bf(b3.x) | ((unsigned)f2bf(b3.y) << 16);
      w1.w = (unsigned)f2bf(b3.z) | ((unsigned)f2bf(b3.w) << 16);
      *(uint4*)&Bs[srow * 72 + sc]     = w0;
      *(uint4*)&Bs[srow * 72 + sc + 8] = w1;
    }
    __syncthreads();
    #pragma unroll
    for (int ks = 0; ks < 2; ks++) {
      bf16x8 a0 = *(const bf16x8*)&As[(wr * 32 + q) * 72      + ks * 32 + g * 8];
      bf16x8 a1 = *(const bf16x8*)&As[(wr * 32 + 16 + q) * 72 + ks * 32 + g * 8];
      bf16x8 b0 = *(const bf16x8*)&Bs[(wc * 32 + q) * 72      + ks * 32 + g * 8];
      bf16x8 b1 = *(const bf16x8*)&Bs[(wc * 32 + 16 + q) * 72 + ks * 32 + g * 8];
      acc[0][0] = __builtin_amdgcn_mfma_f32_16x16x32_bf16(a0, b0, acc[0][0], 0, 0, 0);
      acc[0][1] = __builtin_amdgcn_mfma_f32_16x16x32_bf16(a0, b1, acc[0][1], 0, 0, 0);
      acc[1][0] = __builtin_amdgcn_mfma_f32_16x16x32_bf16(a1, b0, acc[1][0], 0, 0, 0);
      acc[1][1] = __builtin_amdgcn_mfma_f32_16x16x32_bf16(a1, b1, acc[1][1], 0, 0, 0);
    }
  }

  #pragma unroll
  for (int i = 0; i < 2; i++) {
    #pragma unroll
    for (int j = 0; j < 2; j++) {
      const int m0 = bm + wr * 32 + i * 16 + g * 4;
      const int n  = bn + wc * 32 + j * 16 + q;
      if (MODE == 0) {
        float uu = bias0[n], vv = bias1[n];
        #pragma unroll
        for (int r = 0; r < 4; r++) {
          C16a[(m0 + r) * DIM + n] = f2bf((acc[i][j][r] + uu) * 0.125f);
          C16b[(m0 + r) * DIM + n] = f2bf((acc[i][j][r] + vv) * 0.125f);
        }
      } else if (MODE == 1) {
        #pragma unroll
        for (int r = 0; r < 4; r++)
          C16a[(m0 + r) * DIM + n] = f2bf(acc[i][j][r]);
      } else if (MODE == 2) {
        ushort4 pk;
        pk.x = f2bf(acc[i][j][0]); pk.y = f2bf(acc[i][j][1]);
        pk.z = f2bf(acc[i][j][2]); pk.w = f2bf(acc[i][j][3]);
        *(ushort4*)&C16a[n * DIM + m0] = pk;           // vvpT[n][t]
      } else {
        float bb = bias0[n];
        #pragma unroll
        for (int r = 0; r < 4; r++)
          Cf[(m0 + r) * DIM + n] = acc[i][j][r] + bb;
      }
    }
  }
}

// ---------- fused MFMA flash attention (swapped-operand layout) ----------
// Block = (head, 64 s-rows); wave w owns s in [s0+16w, s0+16w+16).
// S^T = mfma(K, Qu); G^T = mfma(Rc, Qv) over the diagonal band; P^T -> PV.
__global__ __launch_bounds__(256) void attn_mfma(
    const unsigned short* __restrict__ qu, const unsigned short* __restrict__ qv,
    const unsigned short* __restrict__ kkp, const unsigned short* __restrict__ vvpT,
    const unsigned short* __restrict__ Rc, unsigned short* __restrict__ attout)
{
  __shared__ short Ks[64 * 72];     // K tile  [t][d]
  __shared__ short Vs[64 * 72];     // V^T tile [d][t]
  __shared__ short Rcs[128 * 72];   // Rc band [p][d]
  __shared__ short Ps[64 * 72];     // P  [s][t]
  __shared__ float Gs[64 * 84];     // G  [s][p_rel]

  const int tid = threadIdx.x;
  const int h  = blockIdx.x >> 4;
  const int s0 = (blockIdx.x & 15) * 64;
  const int w = tid >> 6, l = tid & 63, g = l >> 4, q = l & 15;
  const int col0 = h * HDIM;

  // hoisted Q fragments (B-operand: col = s, k = d)
  const int sw = s0 + w * 16 + q;
  bf16x8 qub[2], qvb[2];
  qub[0] = *(const bf16x8*)&qu[sw * DIM + col0 + g * 8];
  qub[1] = *(const bf16x8*)&qu[sw * DIM + col0 + 32 + g * 8];
  qvb[0] = *(const bf16x8*)&qv[sw * DIM + col0 + g * 8];
  qvb[1] = *(const bf16x8*)&qv[sw * DIM + col0 + 32 + g * 8];

  f32x4 accO[4] = {};
  float m_run = -1e30f, l_run = 0.f;

  const int srow = tid >> 2, sc = (tid & 3) * 16;
  const int rrow = tid >> 1, rc = (tid & 1) * 32;

  for (int t0 = 0; t0 < SQ; t0 += 64) {
    __syncthreads();
    {
      const uint4* ksrc = (const uint4*)&kkp[(t0 + srow) * DIM + col0 + sc];
      *(uint4*)&Ks[srow * 72 + sc]     = ksrc[0];
      *(uint4*)&Ks[srow * 72 + sc + 8] = ksrc[1];
      const uint4* vsrc = (const uint4*)&vvpT[(col0 + srow) * SQ + t0 + sc];
      *(uint4*)&Vs[srow * 72 + sc]     = vsrc[0];
      *(uint4*)&Vs[srow * 72 + sc + 8] = vsrc[1];
      const int P0 = s0 - t0 + 960;
      const uint4* rsrc = (const uint4*)&Rc[(P0 + rrow) * HDIM + rc];
      *(uint4*)&Rcs[rrow * 72 + rc]      = rsrc[0];
      *(uint4*)&Rcs[rrow * 72 + rc + 8]  = rsrc[1];
      *(uint4*)&Rcs[rrow * 72 + rc + 16] = rsrc[2];
      *(uint4*)&Rcs[rrow * 72 + rc + 24] = rsrc[3];
    }
    __syncthreads();

    f32x4 accS[4] = {};
    f32x4 accG[5] = {};
    #pragma unroll
    for (int ks = 0; ks < 2; ks++) {
      #pragma unroll
      for (int tf = 0; tf < 4; tf++) {
        bf16x8 a = *(const bf16x8*)&Ks[(tf * 16 + q) * 72 + ks * 32 + g * 8];
        accS[tf] = __builtin_amdgcn_mfma_f32_16x16x32_bf16(a, qub[ks], accS[tf], 0, 0, 0);
      }
      #pragma unroll
      for (int pf = 0; pf < 5; pf++) {
        bf16x8 a = *(const bf16x8*)&Rcs[(w * 16 + pf * 16 + q) * 72 + ks * 32 + g * 8];
        accG[pf] = __builtin_amdgcn_mfma_f32_16x16x32_bf16(a, qvb[ks], accG[pf], 0, 0, 0);
      }
    }
    // G^T acc (row p_rel = pf*16+g*4+r, col s=q)  ->  Gs[s][p_rel]
    #pragma unroll
    for (int pf = 0; pf < 5; pf++)
      *(f32x4*)&Gs[(w * 16 + q) * 84 + pf * 16 + g * 4] = accG[pf];

    // logits + online softmax (lane owns column s = q; 16 t-values/lane)
    float pvals[16];
    float mx = -1e30f;
    #pragma unroll
    for (int tf = 0; tf < 4; tf++) {
      #pragma unroll
      for (int r = 0; r < 4; r++) {
        int t_rel = tf * 16 + g * 4 + r;
        float sval = accS[tf][r] + Gs[(w * 16 + q) * 84 + (q - t_rel + 63)];
        pvals[tf * 4 + r] = sval;
        mx = fmaxf(mx, sval);
      }
    }
    mx = fmaxf(mx, __shfl_xor(mx, 16));
    mx = fmaxf(mx, __shfl_xor(mx, 32));
    float m_new = fmaxf(m_run, mx);
    float scale = __expf(m_run - m_new);
    float rsum = 0.f;
    #pragma unroll
    for (int i = 0; i < 16; i++) {
      float p = __expf(pvals[i] - m_new);
      pvals[i] = p;
      rsum += p;
    }
    rsum += __shfl_xor(rsum, 16);
    rsum += __shfl_xor(rsum, 32);
    l_run = l_run * scale + rsum;
    m_run = m_new;
    #pragma unroll
    for (int df = 0; df < 4; df++) {
      #pragma unroll
      for (int r = 0; r < 4; r++) accO[df][r] *= scale;
    }
    // P^T (acc rows = t) -> Ps[s][t], 4 bf16 packed per frag
    #pragma unroll
    for (int tf = 0; tf < 4; tf++) {
      unsigned int lo = (unsigned)f2bf(pvals[tf * 4 + 0]) | ((unsigned)f2bf(pvals[tf * 4 + 1]) << 16);
      unsigned int hi = (unsigned)f2bf(pvals[tf * 4 + 2]) | ((unsigned)f2bf(pvals[tf * 4 + 3]) << 16);
      *(uint2*)&Ps[(w * 16 + q) * 72 + tf * 16 + g * 4] = make_uint2(lo, hi);
    }
    // PV: out^T[d][s] += V^T[d][t] * P[s][t]
    #pragma unroll
    for (int ks = 0; ks < 2; ks++) {
      bf16x8 b = *(const bf16x8*)&Ps[(w * 16 + q) * 72 + ks * 32 + g * 8];
      #pragma unroll
      for (int df = 0; df < 4; df++) {
        bf16x8 a = *(const bf16x8*)&Vs[(df * 16 + q) * 72 + ks * 32 + g * 8];
        accO[df] = __builtin_amdgcn_mfma_f32_16x16x32_bf16(a, b, accO[df], 0, 0, 0);
      }
    }
  }

  const float inv = 1.f / l_run;
  #pragma unroll
  for (int df = 0; df < 4; df++) {
    ushort4 pk;
    pk.x = f2bf(accO[df][0] * inv);
    pk.y = f2bf(accO[df][1] * inv);
    pk.z = f2bf(accO[df][2] * inv);
    pk.w = f2bf(accO[df][3] * inv);
    *(ushort4*)&attout[sw * DIM + col0 + df * 16 + g * 4] = pk;
  }
}

extern "C" void kernel_launch(void* const* d_in, const int* in_sizes, int n_in,
                              void* d_out, int out_size, void* d_ws, size_t ws_size,
                              hipStream_t stream) {
  const float* value = (const float*)d_in[0];
  const float* key   = (const float*)d_in[1];
  const float* query = (const float*)d_in[2];
  const float* Wq    = (const float*)d_in[3];
  const float* Wk    = (const float*)d_in[4];
  const float* Wv    = (const float*)d_in[5];
  const float* u     = (const float*)d_in[6];
  const float* v     = (const float*)d_in[7];
  const float* Wo    = (const float*)d_in[8];
  const float* bo    = (const float*)d_in[9];
  float* out = (float*)d_out;

  unsigned short* ws = (unsigned short*)d_ws;
  unsigned short* qu_p   = ws;                  // 1M bf16 each
  unsigned short* qv_p   = qu_p   + (1 << 20);
  unsigned short* kkp    = qv_p   + (1 << 20);
  unsigned short* vvpT   = kkp    + (1 << 20);
  unsigned short* attout = vvpT   + (1 << 20);
  unsigned short* Rc     = attout + (1 << 20);  // 2048*64

  relpos_kernel<<<256, 256, 0, stream>>>(Rc);

  dim3 gg(16, 16);
  gemm16<0><<<gg, 256, 0, stream>>>(query, Wq, qu_p, qv_p, nullptr, u, v);
  gemm16<1><<<gg, 256, 0, stream>>>(key,   Wk, kkp,  nullptr, nullptr, nullptr, nullptr);
  gemm16<2><<<gg, 256, 0, stream>>>(value, Wv, vvpT, nullptr, nullptr, nullptr, nullptr);

  attn_mfma<<<NH * (SQ / 64), 256, 0, stream>>>(qu_p, qv_p, kkp, vvpT, Rc, attout);

  gemm16<3><<<gg, 256, 0, stream>>>(attout, Wo, nullptr, nullptr, out, bo, nullptr);
}

// Round 7
// 164.096 us; speedup vs baseline: 3.7035x; 1.2696x over previous
//
#include <hip/hip_runtime.h>
#include <math.h>

#define SQ 1024
#define DIM 1024
#define NH 16
#define HDIM 64

typedef short bf16x8 __attribute__((ext_vector_type(8)));
typedef float f32x4 __attribute__((ext_vector_type(4)));

// RNE fp32->bf16 (bit-identical to hardware v_cvt rounding for non-NaN)
__device__ __forceinline__ unsigned short f2bf(float x) {
  unsigned int u = __builtin_bit_cast(unsigned int, x);
  u += 0x7FFFu + ((u >> 16) & 1u);
  return (unsigned short)(u >> 16);
}
__device__ __forceinline__ unsigned int pkbf(float a, float b) {
  return (unsigned)f2bf(a) | ((unsigned)f2bf(b) << 16);
}

// ---------- prep: convert 7 fp32 matrices to bf16 pool + relpos table ----------
// blocks [0,3584): conversion (7 segments x 1M elems, 8 elems/thread)
// blocks [3584,3840): Rc[p][d], p = s-t+1023  (2048 x 64 bf16)
__global__ __launch_bounds__(256) void prep_kernel(
    const float* __restrict__ query, const float* __restrict__ key_,
    const float* __restrict__ value, const float* __restrict__ Wq,
    const float* __restrict__ Wk, const float* __restrict__ Wv,
    const float* __restrict__ Wo, unsigned short* __restrict__ bfin,
    unsigned short* __restrict__ Rc)
{
  const int b = blockIdx.x;
  if (b < 3584) {
    int gid = b * 256 + threadIdx.x;        // 917504 threads
    int seg = gid >> 17;                    // 131072 threads per segment
    int off = (gid & 131071) * 8;
    const float* s = seg == 0 ? query : seg == 1 ? key_ : seg == 2 ? value :
                     seg == 3 ? Wq : seg == 4 ? Wk : seg == 5 ? Wv : Wo;
    float4 a = *(const float4*)&s[off];
    float4 c = *(const float4*)&s[off + 4];
    uint4 o;
    o.x = pkbf(a.x, a.y); o.y = pkbf(a.z, a.w);
    o.z = pkbf(c.x, c.y); o.w = pkbf(c.z, c.w);
    *(uint4*)&bfin[(size_t)gid * 8] = o;
  } else {
    int gid = (b - 3584) * 256 + threadIdx.x;  // 65536 = 2048 p x 32 f
    int p = gid >> 5, f = gid & 31;
    float pos = (float)(p - (SQ - 1));
    float invf = expf(-0.28782313662425575f * (float)f);   // 10000^(-f/32)
    float ang = pos * invf;
    Rc[p * HDIM + 2 * f]     = f2bf(sinf(ang));
    Rc[p * HDIM + 2 * f + 1] = f2bf(cosf(ang));
  }
}

// ---------- merged Q/K/V projection GEMM (bf16 MFMA), z selects matrix ----------
// z=0: qu = bf16((acc+u[n])*0.125), qv = bf16((acc+v[n])*0.125)
// z=1: kkp = bf16(acc)
// z=2: vvpT[n][m] = bf16(acc)   (transposed store)
__global__ __launch_bounds__(256) void gemm_qkv(
    const unsigned short* __restrict__ bfin,
    unsigned short* __restrict__ qu, unsigned short* __restrict__ qv,
    unsigned short* __restrict__ kkp, unsigned short* __restrict__ vvpT,
    const float* __restrict__ u, const float* __restrict__ v)
{
  __shared__ short As[64 * 72];
  __shared__ short Bs[64 * 72];
  const int z = blockIdx.z;
  const unsigned short* A = bfin + (size_t)z * (1 << 20);        // q / k / v
  const unsigned short* B = bfin + (size_t)(3 + z) * (1 << 20);  // Wq / Wk / Wv
  const int tid = threadIdx.x;
  const int bm = blockIdx.y * 64, bn = blockIdx.x * 64;
  const int w = tid >> 6, l = tid & 63, g = l >> 4, q = l & 15;
  const int wr = w >> 1, wc = w & 1;
  const int srow = tid >> 2, sc = (tid & 3) * 16;
  f32x4 acc[2][2] = {};

  for (int k0 = 0; k0 < DIM; k0 += 64) {
    __syncthreads();
    {
      const uint4* s0 = (const uint4*)&A[(bm + srow) * DIM + k0 + sc];
      *(uint4*)&As[srow * 72 + sc]     = s0[0];
      *(uint4*)&As[srow * 72 + sc + 8] = s0[1];
      const uint4* s1 = (const uint4*)&B[(bn + srow) * DIM + k0 + sc];
      *(uint4*)&Bs[srow * 72 + sc]     = s1[0];
      *(uint4*)&Bs[srow * 72 + sc + 8] = s1[1];
    }
    __syncthreads();
    #pragma unroll
    for (int ks = 0; ks < 2; ks++) {
      bf16x8 a0 = *(const bf16x8*)&As[(wr * 32 + q) * 72      + ks * 32 + g * 8];
      bf16x8 a1 = *(const bf16x8*)&As[(wr * 32 + 16 + q) * 72 + ks * 32 + g * 8];
      bf16x8 b0 = *(const bf16x8*)&Bs[(wc * 32 + q) * 72      + ks * 32 + g * 8];
      bf16x8 b1 = *(const bf16x8*)&Bs[(wc * 32 + 16 + q) * 72 + ks * 32 + g * 8];
      acc[0][0] = __builtin_amdgcn_mfma_f32_16x16x32_bf16(a0, b0, acc[0][0], 0, 0, 0);
      acc[0][1] = __builtin_amdgcn_mfma_f32_16x16x32_bf16(a0, b1, acc[0][1], 0, 0, 0);
      acc[1][0] = __builtin_amdgcn_mfma_f32_16x16x32_bf16(a1, b0, acc[1][0], 0, 0, 0);
      acc[1][1] = __builtin_amdgcn_mfma_f32_16x16x32_bf16(a1, b1, acc[1][1], 0, 0, 0);
    }
  }

  #pragma unroll
  for (int i = 0; i < 2; i++) {
    #pragma unroll
    for (int j = 0; j < 2; j++) {
      const int m0 = bm + wr * 32 + i * 16 + g * 4;
      const int n  = bn + wc * 32 + j * 16 + q;
      if (z == 0) {
        float uu = u[n], vv = v[n];
        #pragma unroll
        for (int r = 0; r < 4; r++) {
          qu[(m0 + r) * DIM + n] = f2bf((acc[i][j][r] + uu) * 0.125f);
          qv[(m0 + r) * DIM + n] = f2bf((acc[i][j][r] + vv) * 0.125f);
        }
      } else if (z == 1) {
        #pragma unroll
        for (int r = 0; r < 4; r++)
          kkp[(m0 + r) * DIM + n] = f2bf(acc[i][j][r]);
      } else {
        ushort4 pk;
        pk.x = f2bf(acc[i][j][0]); pk.y = f2bf(acc[i][j][1]);
        pk.z = f2bf(acc[i][j][2]); pk.w = f2bf(acc[i][j][3]);
        *(ushort4*)&vvpT[n * SQ + m0] = pk;           // vvpT[d][t]
      }
    }
  }
}

// ---------- output GEMM: out(f32) = attout(bf16) @ Wo^T + bo ----------
__global__ __launch_bounds__(256) void gemm_out(
    const unsigned short* __restrict__ A, const unsigned short* __restrict__ B,
    float* __restrict__ out, const float* __restrict__ bo)
{
  __shared__ short As[64 * 72];
  __shared__ short Bs[64 * 72];
  const int tid = threadIdx.x;
  const int bm = blockIdx.y * 64, bn = blockIdx.x * 64;
  const int w = tid >> 6, l = tid & 63, g = l >> 4, q = l & 15;
  const int wr = w >> 1, wc = w & 1;
  const int srow = tid >> 2, sc = (tid & 3) * 16;
  f32x4 acc[2][2] = {};

  for (int k0 = 0; k0 < DIM; k0 += 64) {
    __syncthreads();
    {
      const uint4* s0 = (const uint4*)&A[(bm + srow) * DIM + k0 + sc];
      *(uint4*)&As[srow * 72 + sc]     = s0[0];
      *(uint4*)&As[srow * 72 + sc + 8] = s0[1];
      const uint4* s1 = (const uint4*)&B[(bn + srow) * DIM + k0 + sc];
      *(uint4*)&Bs[srow * 72 + sc]     = s1[0];
      *(uint4*)&Bs[srow * 72 + sc + 8] = s1[1];
    }
    __syncthreads();
    #pragma unroll
    for (int ks = 0; ks < 2; ks++) {
      bf16x8 a0 = *(const bf16x8*)&As[(wr * 32 + q) * 72      + ks * 32 + g * 8];
      bf16x8 a1 = *(const bf16x8*)&As[(wr * 32 + 16 + q) * 72 + ks * 32 + g * 8];
      bf16x8 b0 = *(const bf16x8*)&Bs[(wc * 32 + q) * 72      + ks * 32 + g * 8];
      bf16x8 b1 = *(const bf16x8*)&Bs[(wc * 32 + 16 + q) * 72 + ks * 32 + g * 8];
      acc[0][0] = __builtin_amdgcn_mfma_f32_16x16x32_bf16(a0, b0, acc[0][0], 0, 0, 0);
      acc[0][1] = __builtin_amdgcn_mfma_f32_16x16x32_bf16(a0, b1, acc[0][1], 0, 0, 0);
      acc[1][0] = __builtin_amdgcn_mfma_f32_16x16x32_bf16(a1, b0, acc[1][0], 0, 0, 0);
      acc[1][1] = __builtin_amdgcn_mfma_f32_16x16x32_bf16(a1, b1, acc[1][1], 0, 0, 0);
    }
  }

  #pragma unroll
  for (int i = 0; i < 2; i++) {
    #pragma unroll
    for (int j = 0; j < 2; j++) {
      const int m0 = bm + wr * 32 + i * 16 + g * 4;
      const int n  = bn + wc * 32 + j * 16 + q;
      float bb = bo[n];
      #pragma unroll
      for (int r = 0; r < 4; r++)
        out[(m0 + r) * DIM + n] = acc[i][j][r] + bb;
    }
  }
}

// ---------- fused MFMA flash attention (swapped-operand layout) ----------
__global__ __launch_bounds__(256) void attn_mfma(
    const unsigned short* __restrict__ qu, const unsigned short* __restrict__ qv,
    const unsigned short* __restrict__ kkp, const unsigned short* __restrict__ vvpT,
    const unsigned short* __restrict__ Rc, unsigned short* __restrict__ attout)
{
  __shared__ short Ks[64 * 72];     // K tile  [t][d]
  __shared__ short Vs[64 * 72];     // V^T tile [d][t]
  __shared__ short Rcs[128 * 72];   // Rc band [p][d]
  __shared__ short Ps[64 * 72];     // P  [s][t]
  __shared__ float Gs[64 * 84];     // G  [s][p_rel]

  const int tid = threadIdx.x;
  const int h  = blockIdx.x >> 4;
  const int s0 = (blockIdx.x & 15) * 64;
  const int w = tid >> 6, l = tid & 63, g = l >> 4, q = l & 15;
  const int col0 = h * HDIM;

  const int sw = s0 + w * 16 + q;
  bf16x8 qub[2], qvb[2];
  qub[0] = *(const bf16x8*)&qu[sw * DIM + col0 + g * 8];
  qub[1] = *(const bf16x8*)&qu[sw * DIM + col0 + 32 + g * 8];
  qvb[0] = *(const bf16x8*)&qv[sw * DIM + col0 + g * 8];
  qvb[1] = *(const bf16x8*)&qv[sw * DIM + col0 + 32 + g * 8];

  f32x4 accO[4] = {};
  float m_run = -1e30f, l_run = 0.f;

  const int srow = tid >> 2, sc = (tid & 3) * 16;
  const int rrow = tid >> 1, rc = (tid & 1) * 32;

  for (int t0 = 0; t0 < SQ; t0 += 64) {
    __syncthreads();
    {
      const uint4* ksrc = (const uint4*)&kkp[(t0 + srow) * DIM + col0 + sc];
      *(uint4*)&Ks[srow * 72 + sc]     = ksrc[0];
      *(uint4*)&Ks[srow * 72 + sc + 8] = ksrc[1];
      const uint4* vsrc = (const uint4*)&vvpT[(col0 + srow) * SQ + t0 + sc];
      *(uint4*)&Vs[srow * 72 + sc]     = vsrc[0];
      *(uint4*)&Vs[srow * 72 + sc + 8] = vsrc[1];
      const int P0 = s0 - t0 + 960;
      const uint4* rsrc = (const uint4*)&Rc[(P0 + rrow) * HDIM + rc];
      *(uint4*)&Rcs[rrow * 72 + rc]      = rsrc[0];
      *(uint4*)&Rcs[rrow * 72 + rc + 8]  = rsrc[1];
      *(uint4*)&Rcs[rrow * 72 + rc + 16] = rsrc[2];
      *(uint4*)&Rcs[rrow * 72 + rc + 24] = rsrc[3];
    }
    __syncthreads();

    f32x4 accS[4] = {};
    f32x4 accG[5] = {};
    #pragma unroll
    for (int ks = 0; ks < 2; ks++) {
      #pragma unroll
      for (int tf = 0; tf < 4; tf++) {
        bf16x8 a = *(const bf16x8*)&Ks[(tf * 16 + q) * 72 + ks * 32 + g * 8];
        accS[tf] = __builtin_amdgcn_mfma_f32_16x16x32_bf16(a, qub[ks], accS[tf], 0, 0, 0);
      }
      #pragma unroll
      for (int pf = 0; pf < 5; pf++) {
        bf16x8 a = *(const bf16x8*)&Rcs[(w * 16 + pf * 16 + q) * 72 + ks * 32 + g * 8];
        accG[pf] = __builtin_amdgcn_mfma_f32_16x16x32_bf16(a, qvb[ks], accG[pf], 0, 0, 0);
      }
    }
    #pragma unroll
    for (int pf = 0; pf < 5; pf++)
      *(f32x4*)&Gs[(w * 16 + q) * 84 + pf * 16 + g * 4] = accG[pf];

    float pvals[16];
    float mx = -1e30f;
    #pragma unroll
    for (int tf = 0; tf < 4; tf++) {
      #pragma unroll
      for (int r = 0; r < 4; r++) {
        int t_rel = tf * 16 + g * 4 + r;
        float sval = accS[tf][r] + Gs[(w * 16 + q) * 84 + (q - t_rel + 63)];
        pvals[tf * 4 + r] = sval;
        mx = fmaxf(mx, sval);
      }
    }
    mx = fmaxf(mx, __shfl_xor(mx, 16));
    mx = fmaxf(mx, __shfl_xor(mx, 32));
    float m_new = fmaxf(m_run, mx);
    float scale = __expf(m_run - m_new);
    float rsum = 0.f;
    #pragma unroll
    for (int i = 0; i < 16; i++) {
      float p = __expf(pvals[i] - m_new);
      pvals[i] = p;
      rsum += p;
    }
    rsum += __shfl_xor(rsum, 16);
    rsum += __shfl_xor(rsum, 32);
    l_run = l_run * scale + rsum;
    m_run = m_new;
    #pragma unroll
    for (int df = 0; df < 4; df++) {
      #pragma unroll
      for (int r = 0; r < 4; r++) accO[df][r] *= scale;
    }
    #pragma unroll
    for (int tf = 0; tf < 4; tf++) {
      unsigned int lo = pkbf(pvals[tf * 4 + 0], pvals[tf * 4 + 1]);
      unsigned int hi = pkbf(pvals[tf * 4 + 2], pvals[tf * 4 + 3]);
      *(uint2*)&Ps[(w * 16 + q) * 72 + tf * 16 + g * 4] = make_uint2(lo, hi);
    }
    #pragma unroll
    for (int ks = 0; ks < 2; ks++) {
      bf16x8 b = *(const bf16x8*)&Ps[(w * 16 + q) * 72 + ks * 32 + g * 8];
      #pragma unroll
      for (int df = 0; df < 4; df++) {
        bf16x8 a = *(const bf16x8*)&Vs[(df * 16 + q) * 72 + ks * 32 + g * 8];
        accO[df] = __builtin_amdgcn_mfma_f32_16x16x32_bf16(a, b, accO[df], 0, 0, 0);
      }
    }
  }

  const float inv = 1.f / l_run;
  #pragma unroll
  for (int df = 0; df < 4; df++) {
    unsigned int lo = pkbf(accO[df][0] * inv, accO[df][1] * inv);
    unsigned int hi = pkbf(accO[df][2] * inv, accO[df][3] * inv);
    *(uint2*)&attout[sw * DIM + col0 + df * 16 + g * 4] = make_uint2(lo, hi);
  }
}

extern "C" void kernel_launch(void* const* d_in, const int* in_sizes, int n_in,
                              void* d_out, int out_size, void* d_ws, size_t ws_size,
                              hipStream_t stream) {
  const float* value = (const float*)d_in[0];
  const float* key   = (const float*)d_in[1];
  const float* query = (const float*)d_in[2];
  const float* Wq    = (const float*)d_in[3];
  const float* Wk    = (const float*)d_in[4];
  const float* Wv    = (const float*)d_in[5];
  const float* u     = (const float*)d_in[6];
  const float* v     = (const float*)d_in[7];
  const float* Wo    = (const float*)d_in[8];
  const float* bo    = (const float*)d_in[9];
  float* out = (float*)d_out;

  unsigned short* ws = (unsigned short*)d_ws;
  unsigned short* bfin   = ws;                       // 7 x 1M bf16: q,k,v,Wq,Wk,Wv,Wo
  unsigned short* qu_p   = bfin   + 7 * (1 << 20);
  unsigned short* qv_p   = qu_p   + (1 << 20);
  unsigned short* kkp    = qv_p   + (1 << 20);
  unsigned short* vvpT   = kkp    + (1 << 20);
  unsigned short* attout = vvpT   + (1 << 20);
  unsigned short* Rc     = attout + (1 << 20);       // 2048*64

  prep_kernel<<<3840, 256, 0, stream>>>(query, key, value, Wq, Wk, Wv, Wo, bfin, Rc);

  dim3 gqkv(16, 16, 3);
  gemm_qkv<<<gqkv, 256, 0, stream>>>(bfin, qu_p, qv_p, kkp, vvpT, u, v);

  attn_mfma<<<NH * (SQ / 64), 256, 0, stream>>>(qu_p, qv_p, kkp, vvpT, Rc, attout);

  dim3 gg(16, 16);
  gemm_out<<<gg, 256, 0, stream>>>(attout, bfin + 6 * (1 << 20), out, bo);
}

// Round 8
// 157.955 us; speedup vs baseline: 3.8475x; 1.0389x over previous
//
#include <hip/hip_runtime.h>
#include <math.h>

#define SQ 1024
#define DIM 1024
#define NH 16
#define HDIM 64

typedef short bf16x8 __attribute__((ext_vector_type(8)));
typedef float f32x4 __attribute__((ext_vector_type(4)));

// RNE fp32->bf16 (bit-identical to hardware v_cvt rounding for non-NaN)
__device__ __forceinline__ unsigned short f2bf(float x) {
  unsigned int u = __builtin_bit_cast(unsigned int, x);
  u += 0x7FFFu + ((u >> 16) & 1u);
  return (unsigned short)(u >> 16);
}
__device__ __forceinline__ unsigned int pkbf(float a, float b) {
  return (unsigned)f2bf(a) | ((unsigned)f2bf(b) << 16);
}

// ---------- prep: convert 7 fp32 matrices to bf16 pool + relpos table ----------
__global__ __launch_bounds__(256) void prep_kernel(
    const float* __restrict__ query, const float* __restrict__ key_,
    const float* __restrict__ value, const float* __restrict__ Wq,
    const float* __restrict__ Wk, const float* __restrict__ Wv,
    const float* __restrict__ Wo, unsigned short* __restrict__ bfin,
    unsigned short* __restrict__ Rc)
{
  const int b = blockIdx.x;
  if (b < 3584) {
    int gid = b * 256 + threadIdx.x;        // 917504 threads
    int seg = gid >> 17;                    // 131072 threads per segment
    int off = (gid & 131071) * 8;
    const float* s = seg == 0 ? query : seg == 1 ? key_ : seg == 2 ? value :
                     seg == 3 ? Wq : seg == 4 ? Wk : seg == 5 ? Wv : Wo;
    float4 a = *(const float4*)&s[off];
    float4 c = *(const float4*)&s[off + 4];
    uint4 o;
    o.x = pkbf(a.x, a.y); o.y = pkbf(a.z, a.w);
    o.z = pkbf(c.x, c.y); o.w = pkbf(c.z, c.w);
    *(uint4*)&bfin[(size_t)gid * 8] = o;
  } else {
    int gid = (b - 3584) * 256 + threadIdx.x;  // 65536 = 2048 p x 32 f
    int p = gid >> 5, f = gid & 31;
    float pos = (float)(p - (SQ - 1));
    float invf = expf(-0.28782313662425575f * (float)f);   // 10000^(-f/32)
    float ang = pos * invf;
    Rc[p * HDIM + 2 * f]     = f2bf(sinf(ang));
    Rc[p * HDIM + 2 * f + 1] = f2bf(cosf(ang));
  }
}

// ---------- merged Q/K/V projection GEMM (bf16 MFMA), z selects matrix ----------
__global__ __launch_bounds__(256) void gemm_qkv(
    const unsigned short* __restrict__ bfin,
    unsigned short* __restrict__ qu, unsigned short* __restrict__ qv,
    unsigned short* __restrict__ kkp, unsigned short* __restrict__ vvpT,
    const float* __restrict__ u, const float* __restrict__ v)
{
  __shared__ short As[64 * 72];
  __shared__ short Bs[64 * 72];
  const int z = blockIdx.z;
  const unsigned short* A = bfin + (size_t)z * (1 << 20);        // q / k / v
  const unsigned short* B = bfin + (size_t)(3 + z) * (1 << 20);  // Wq / Wk / Wv
  const int tid = threadIdx.x;
  const int bm = blockIdx.y * 64, bn = blockIdx.x * 64;
  const int w = tid >> 6, l = tid & 63, g = l >> 4, q = l & 15;
  const int wr = w >> 1, wc = w & 1;
  const int srow = tid >> 2, sc = (tid & 3) * 16;
  f32x4 acc[2][2] = {};

  for (int k0 = 0; k0 < DIM; k0 += 64) {
    __syncthreads();
    {
      const uint4* s0 = (const uint4*)&A[(bm + srow) * DIM + k0 + sc];
      *(uint4*)&As[srow * 72 + sc]     = s0[0];
      *(uint4*)&As[srow * 72 + sc + 8] = s0[1];
      const uint4* s1 = (const uint4*)&B[(bn + srow) * DIM + k0 + sc];
      *(uint4*)&Bs[srow * 72 + sc]     = s1[0];
      *(uint4*)&Bs[srow * 72 + sc + 8] = s1[1];
    }
    __syncthreads();
    #pragma unroll
    for (int ks = 0; ks < 2; ks++) {
      bf16x8 a0 = *(const bf16x8*)&As[(wr * 32 + q) * 72      + ks * 32 + g * 8];
      bf16x8 a1 = *(const bf16x8*)&As[(wr * 32 + 16 + q) * 72 + ks * 32 + g * 8];
      bf16x8 b0 = *(const bf16x8*)&Bs[(wc * 32 + q) * 72      + ks * 32 + g * 8];
      bf16x8 b1 = *(const bf16x8*)&Bs[(wc * 32 + 16 + q) * 72 + ks * 32 + g * 8];
      acc[0][0] = __builtin_amdgcn_mfma_f32_16x16x32_bf16(a0, b0, acc[0][0], 0, 0, 0);
      acc[0][1] = __builtin_amdgcn_mfma_f32_16x16x32_bf16(a0, b1, acc[0][1], 0, 0, 0);
      acc[1][0] = __builtin_amdgcn_mfma_f32_16x16x32_bf16(a1, b0, acc[1][0], 0, 0, 0);
      acc[1][1] = __builtin_amdgcn_mfma_f32_16x16x32_bf16(a1, b1, acc[1][1], 0, 0, 0);
    }
  }

  #pragma unroll
  for (int i = 0; i < 2; i++) {
    #pragma unroll
    for (int j = 0; j < 2; j++) {
      const int m0 = bm + wr * 32 + i * 16 + g * 4;
      const int n  = bn + wc * 32 + j * 16 + q;
      if (z == 0) {
        float uu = u[n], vv = v[n];
        #pragma unroll
        for (int r = 0; r < 4; r++) {
          qu[(m0 + r) * DIM + n] = f2bf((acc[i][j][r] + uu) * 0.125f);
          qv[(m0 + r) * DIM + n] = f2bf((acc[i][j][r] + vv) * 0.125f);
        }
      } else if (z == 1) {
        #pragma unroll
        for (int r = 0; r < 4; r++)
          kkp[(m0 + r) * DIM + n] = f2bf(acc[i][j][r]);
      } else {
        ushort4 pk;
        pk.x = f2bf(acc[i][j][0]); pk.y = f2bf(acc[i][j][1]);
        pk.z = f2bf(acc[i][j][2]); pk.w = f2bf(acc[i][j][3]);
        *(ushort4*)&vvpT[n * SQ + m0] = pk;           // vvpT[d][t]
      }
    }
  }
}

// ---------- output GEMM: out(f32) = attout(bf16) @ Wo^T + bo ----------
__global__ __launch_bounds__(256) void gemm_out(
    const unsigned short* __restrict__ A, const unsigned short* __restrict__ B,
    float* __restrict__ out, const float* __restrict__ bo)
{
  __shared__ short As[64 * 72];
  __shared__ short Bs[64 * 72];
  const int tid = threadIdx.x;
  const int bm = blockIdx.y * 64, bn = blockIdx.x * 64;
  const int w = tid >> 6, l = tid & 63, g = l >> 4, q = l & 15;
  const int wr = w >> 1, wc = w & 1;
  const int srow = tid >> 2, sc = (tid & 3) * 16;
  f32x4 acc[2][2] = {};

  for (int k0 = 0; k0 < DIM; k0 += 64) {
    __syncthreads();
    {
      const uint4* s0 = (const uint4*)&A[(bm + srow) * DIM + k0 + sc];
      *(uint4*)&As[srow * 72 + sc]     = s0[0];
      *(uint4*)&As[srow * 72 + sc + 8] = s0[1];
      const uint4* s1 = (const uint4*)&B[(bn + srow) * DIM + k0 + sc];
      *(uint4*)&Bs[srow * 72 + sc]     = s1[0];
      *(uint4*)&Bs[srow * 72 + sc + 8] = s1[1];
    }
    __syncthreads();
    #pragma unroll
    for (int ks = 0; ks < 2; ks++) {
      bf16x8 a0 = *(const bf16x8*)&As[(wr * 32 + q) * 72      + ks * 32 + g * 8];
      bf16x8 a1 = *(const bf16x8*)&As[(wr * 32 + 16 + q) * 72 + ks * 32 + g * 8];
      bf16x8 b0 = *(const bf16x8*)&Bs[(wc * 32 + q) * 72      + ks * 32 + g * 8];
      bf16x8 b1 = *(const bf16x8*)&Bs[(wc * 32 + 16 + q) * 72 + ks * 32 + g * 8];
      acc[0][0] = __builtin_amdgcn_mfma_f32_16x16x32_bf16(a0, b0, acc[0][0], 0, 0, 0);
      acc[0][1] = __builtin_amdgcn_mfma_f32_16x16x32_bf16(a0, b1, acc[0][1], 0, 0, 0);
      acc[1][0] = __builtin_amdgcn_mfma_f32_16x16x32_bf16(a1, b0, acc[1][0], 0, 0, 0);
      acc[1][1] = __builtin_amdgcn_mfma_f32_16x16x32_bf16(a1, b1, acc[1][1], 0, 0, 0);
    }
  }

  #pragma unroll
  for (int i = 0; i < 2; i++) {
    #pragma unroll
    for (int j = 0; j < 2; j++) {
      const int m0 = bm + wr * 32 + i * 16 + g * 4;
      const int n  = bn + wc * 32 + j * 16 + q;
      float bb = bo[n];
      #pragma unroll
      for (int r = 0; r < 4; r++)
        out[(m0 + r) * DIM + n] = acc[i][j][r] + bb;
    }
  }
}

// ---------- fused MFMA flash attention, split-t (blockIdx.y = t-half) ----------
// Writes raw partial O (no 1/l), plus per-row (m, l) for the combine pass.
__global__ __launch_bounds__(256, 2) void attn_mfma(
    const unsigned short* __restrict__ qu, const unsigned short* __restrict__ qv,
    const unsigned short* __restrict__ kkp, const unsigned short* __restrict__ vvpT,
    const unsigned short* __restrict__ Rc, float* __restrict__ PO,
    float* __restrict__ ML)
{
  __shared__ short Ks[64 * 72];     // K tile  [t][d]
  __shared__ short Vs[64 * 72];     // V^T tile [d][t]
  __shared__ short Rcs[128 * 72];   // Rc band [p][d]
  __shared__ short Ps[64 * 72];     // P  [s][t]
  __shared__ float Gs[64 * 84];     // G  [s][p_rel]

  const int tid = threadIdx.x;
  const int h  = blockIdx.x >> 4;
  const int s0 = (blockIdx.x & 15) * 64;
  const int th = blockIdx.y;
  const int w = tid >> 6, l = tid & 63, g = l >> 4, q = l & 15;
  const int col0 = h * HDIM;

  const int sw = s0 + w * 16 + q;
  bf16x8 qub[2], qvb[2];
  qub[0] = *(const bf16x8*)&qu[sw * DIM + col0 + g * 8];
  qub[1] = *(const bf16x8*)&qu[sw * DIM + col0 + 32 + g * 8];
  qvb[0] = *(const bf16x8*)&qv[sw * DIM + col0 + g * 8];
  qvb[1] = *(const bf16x8*)&qv[sw * DIM + col0 + 32 + g * 8];

  f32x4 accO[4] = {};
  float m_run = -1e30f, l_run = 0.f;

  const int srow = tid >> 2, sc = (tid & 3) * 16;
  const int rrow = tid >> 1, rc = (tid & 1) * 32;

  for (int t0 = th * 512; t0 < th * 512 + 512; t0 += 64) {
    __syncthreads();
    {
      const uint4* ksrc = (const uint4*)&kkp[(t0 + srow) * DIM + col0 + sc];
      *(uint4*)&Ks[srow * 72 + sc]     = ksrc[0];
      *(uint4*)&Ks[srow * 72 + sc + 8] = ksrc[1];
      const uint4* vsrc = (const uint4*)&vvpT[(col0 + srow) * SQ + t0 + sc];
      *(uint4*)&Vs[srow * 72 + sc]     = vsrc[0];
      *(uint4*)&Vs[srow * 72 + sc + 8] = vsrc[1];
      const int P0 = s0 - t0 + 960;   // in [0, 1920]
      const uint4* rsrc = (const uint4*)&Rc[(P0 + rrow) * HDIM + rc];
      *(uint4*)&Rcs[rrow * 72 + rc]      = rsrc[0];
      *(uint4*)&Rcs[rrow * 72 + rc + 8]  = rsrc[1];
      *(uint4*)&Rcs[rrow * 72 + rc + 16] = rsrc[2];
      *(uint4*)&Rcs[rrow * 72 + rc + 24] = rsrc[3];
    }
    __syncthreads();

    f32x4 accS[4] = {};
    f32x4 accG[5] = {};
    #pragma unroll
    for (int ks = 0; ks < 2; ks++) {
      #pragma unroll
      for (int tf = 0; tf < 4; tf++) {
        bf16x8 a = *(const bf16x8*)&Ks[(tf * 16 + q) * 72 + ks * 32 + g * 8];
        accS[tf] = __builtin_amdgcn_mfma_f32_16x16x32_bf16(a, qub[ks], accS[tf], 0, 0, 0);
      }
      #pragma unroll
      for (int pf = 0; pf < 5; pf++) {
        bf16x8 a = *(const bf16x8*)&Rcs[(w * 16 + pf * 16 + q) * 72 + ks * 32 + g * 8];
        accG[pf] = __builtin_amdgcn_mfma_f32_16x16x32_bf16(a, qvb[ks], accG[pf], 0, 0, 0);
      }
    }
    #pragma unroll
    for (int pf = 0; pf < 5; pf++)
      *(f32x4*)&Gs[(w * 16 + q) * 84 + pf * 16 + g * 4] = accG[pf];

    float pvals[16];
    float mx = -1e30f;
    #pragma unroll
    for (int tf = 0; tf < 4; tf++) {
      #pragma unroll
      for (int r = 0; r < 4; r++) {
        int t_rel = tf * 16 + g * 4 + r;
        float sval = accS[tf][r] + Gs[(w * 16 + q) * 84 + (q - t_rel + 63)];
        pvals[tf * 4 + r] = sval;
        mx = fmaxf(mx, sval);
      }
    }
    mx = fmaxf(mx, __shfl_xor(mx, 16));
    mx = fmaxf(mx, __shfl_xor(mx, 32));
    float m_new = fmaxf(m_run, mx);
    float scale = __expf(m_run - m_new);
    float rsum = 0.f;
    #pragma unroll
    for (int i = 0; i < 16; i++) {
      float p = __expf(pvals[i] - m_new);
      pvals[i] = p;
      rsum += p;
    }
    rsum += __shfl_xor(rsum, 16);
    rsum += __shfl_xor(rsum, 32);
    l_run = l_run * scale + rsum;
    m_run = m_new;
    #pragma unroll
    for (int df = 0; df < 4; df++) {
      #pragma unroll
      for (int r = 0; r < 4; r++) accO[df][r] *= scale;
    }
    #pragma unroll
    for (int tf = 0; tf < 4; tf++) {
      unsigned int lo = pkbf(pvals[tf * 4 + 0], pvals[tf * 4 + 1]);
      unsigned int hi = pkbf(pvals[tf * 4 + 2], pvals[tf * 4 + 3]);
      *(uint2*)&Ps[(w * 16 + q) * 72 + tf * 16 + g * 4] = make_uint2(lo, hi);
    }
    #pragma unroll
    for (int ks = 0; ks < 2; ks++) {
      bf16x8 b = *(const bf16x8*)&Ps[(w * 16 + q) * 72 + ks * 32 + g * 8];
      #pragma unroll
      for (int df = 0; df < 4; df++) {
        bf16x8 a = *(const bf16x8*)&Vs[(df * 16 + q) * 72 + ks * 32 + g * 8];
        accO[df] = __builtin_amdgcn_mfma_f32_16x16x32_bf16(a, b, accO[df], 0, 0, 0);
      }
    }
  }

  // partial store: PO[tile][s_local][d] (f32), ML[tile][s_local][{m,l}]
  const int tile = blockIdx.x * 2 + th;
  float* POt = PO + (size_t)tile * 4096;
  const int sl = w * 16 + q;
  #pragma unroll
  for (int df = 0; df < 4; df++)
    *(f32x4*)&POt[sl * 64 + df * 16 + g * 4] = accO[df];
  if (g == 0) {
    ML[tile * 128 + sl * 2]     = m_run;
    ML[tile * 128 + sl * 2 + 1] = l_run;
  }
}

// ---------- combine two t-half partials -> attout (bf16) ----------
__global__ __launch_bounds__(256) void attn_combine(
    const float* __restrict__ PO, const float* __restrict__ ML,
    unsigned short* __restrict__ attout)
{
  int gid = blockIdx.x * 256 + threadIdx.x;   // 262144
  int s  = gid >> 8;                          // 0..1023
  int c  = (gid & 255) * 4;                   // column group (h*64 + d)
  int h  = c >> 6;
  int sb = s >> 6, sl = s & 63;
  int tA = (h * 16 + sb) * 2, tB = tA + 1;
  float mA = ML[tA * 128 + sl * 2], lA = ML[tA * 128 + sl * 2 + 1];
  float mB = ML[tB * 128 + sl * 2], lB = ML[tB * 128 + sl * 2 + 1];
  float m = fmaxf(mA, mB);
  float wA = __expf(mA - m), wB = __expf(mB - m);
  float inv = 1.f / (lA * wA + lB * wB);
  wA *= inv; wB *= inv;
  int dl = c & 63;
  float4 a = *(const float4*)&PO[(size_t)tA * 4096 + sl * 64 + dl];
  float4 b = *(const float4*)&PO[(size_t)tB * 4096 + sl * 64 + dl];
  uint2 o;
  o.x = pkbf(a.x * wA + b.x * wB, a.y * wA + b.y * wB);
  o.y = pkbf(a.z * wA + b.z * wB, a.w * wA + b.w * wB);
  *(uint2*)&attout[s * DIM + c] = o;
}

extern "C" void kernel_launch(void* const* d_in, const int* in_sizes, int n_in,
                              void* d_out, int out_size, void* d_ws, size_t ws_size,
                              hipStream_t stream) {
  const float* value = (const float*)d_in[0];
  const float* key   = (const float*)d_in[1];
  const float* query = (const float*)d_in[2];
  const float* Wq    = (const float*)d_in[3];
  const float* Wk    = (const float*)d_in[4];
  const float* Wv    = (const float*)d_in[5];
  const float* u     = (const float*)d_in[6];
  const float* v     = (const float*)d_in[7];
  const float* Wo    = (const float*)d_in[8];
  const float* bo    = (const float*)d_in[9];
  float* out = (float*)d_out;

  unsigned short* ws = (unsigned short*)d_ws;
  unsigned short* bfin   = ws;                       // 7 x 1M bf16: q,k,v,Wq,Wk,Wv,Wo
  unsigned short* qu_p   = bfin   + 7 * (1 << 20);
  unsigned short* qv_p   = qu_p   + (1 << 20);
  unsigned short* kkp    = qv_p   + (1 << 20);
  unsigned short* vvpT   = kkp    + (1 << 20);
  unsigned short* attout = vvpT   + (1 << 20);
  unsigned short* Rc     = attout + (1 << 20);       // 2048*64
  float* PO = (float*)(Rc + 2048 * 64);              // 512 tiles x 64 x 64 f32
  float* ML = PO + (size_t)512 * 4096;               // 512 x 64 x 2 f32

  prep_kernel<<<3840, 256, 0, stream>>>(query, key, value, Wq, Wk, Wv, Wo, bfin, Rc);

  dim3 gqkv(16, 16, 3);
  gemm_qkv<<<gqkv, 256, 0, stream>>>(bfin, qu_p, qv_p, kkp, vvpT, u, v);

  dim3 gattn(NH * (SQ / 64), 2);
  attn_mfma<<<gattn, 256, 0, stream>>>(qu_p, qv_p, kkp, vvpT, Rc, PO, ML);
  attn_combine<<<1024, 256, 0, stream>>>(PO, ML, attout);

  dim3 gg(16, 16);
  gemm_out<<<gg, 256, 0, stream>>>(attout, bfin + 6 * (1 << 20), out, bo);
}

// Round 9
// 141.974 us; speedup vs baseline: 4.2806x; 1.1126x over previous
//
#include <hip/hip_runtime.h>
#include <math.h>

#define SQ 1024
#define DIM 1024
#define NH 16
#define HDIM 64

typedef short bf16x8 __attribute__((ext_vector_type(8)));
typedef float f32x4 __attribute__((ext_vector_type(4)));

// RNE fp32->bf16 (bit-identical to hardware v_cvt rounding for non-NaN)
__device__ __forceinline__ unsigned short f2bf(float x) {
  unsigned int u = __builtin_bit_cast(unsigned int, x);
  u += 0x7FFFu + ((u >> 16) & 1u);
  return (unsigned short)(u >> 16);
}
__device__ __forceinline__ unsigned int pkbf(float a, float b) {
  return (unsigned)f2bf(a) | ((unsigned)f2bf(b) << 16);
}

// ---------- prep: convert 7 fp32 matrices to bf16 pool + relpos table ----------
__global__ __launch_bounds__(256) void prep_kernel(
    const float* __restrict__ query, const float* __restrict__ key_,
    const float* __restrict__ value, const float* __restrict__ Wq,
    const float* __restrict__ Wk, const float* __restrict__ Wv,
    const float* __restrict__ Wo, unsigned short* __restrict__ bfin,
    unsigned short* __restrict__ Rc)
{
  const int b = blockIdx.x;
  if (b < 3584) {
    int gid = b * 256 + threadIdx.x;        // 917504 threads
    int seg = gid >> 17;                    // 131072 threads per segment
    int off = (gid & 131071) * 8;
    const float* s = seg == 0 ? query : seg == 1 ? key_ : seg == 2 ? value :
                     seg == 3 ? Wq : seg == 4 ? Wk : seg == 5 ? Wv : Wo;
    float4 a = *(const float4*)&s[off];
    float4 c = *(const float4*)&s[off + 4];
    uint4 o;
    o.x = pkbf(a.x, a.y); o.y = pkbf(a.z, a.w);
    o.z = pkbf(c.x, c.y); o.w = pkbf(c.z, c.w);
    *(uint4*)&bfin[(size_t)gid * 8] = o;
  } else {
    int gid = (b - 3584) * 256 + threadIdx.x;  // 65536 = 2048 p x 32 f
    int p = gid >> 5, f = gid & 31;
    float pos = (float)(p - (SQ - 1));
    float invf = expf(-0.28782313662425575f * (float)f);   // 10000^(-f/32)
    float ang = pos * invf;
    Rc[p * HDIM + 2 * f]     = f2bf(sinf(ang));
    Rc[p * HDIM + 2 * f + 1] = f2bf(cosf(ang));
  }
}

// ---------- merged Q/K/V projection GEMM, reg-prefetch + LDS double buffer ----------
__global__ __launch_bounds__(256) void gemm_qkv(
    const unsigned short* __restrict__ bfin,
    unsigned short* __restrict__ qu, unsigned short* __restrict__ qv,
    unsigned short* __restrict__ kkp, unsigned short* __restrict__ vvpT,
    const float* __restrict__ u, const float* __restrict__ v)
{
  __shared__ short As[2][64 * 72];
  __shared__ short Bs[2][64 * 72];
  const int z = blockIdx.z;
  const unsigned short* A = bfin + (size_t)z * (1 << 20);        // q / k / v
  const unsigned short* B = bfin + (size_t)(3 + z) * (1 << 20);  // Wq / Wk / Wv
  const int tid = threadIdx.x;
  const int bm = blockIdx.y * 64, bn = blockIdx.x * 64;
  const int w = tid >> 6, l = tid & 63, g = l >> 4, q = l & 15;
  const int wr = w >> 1, wc = w & 1;
  const int srow = tid >> 2, sc = (tid & 3) * 16;
  const unsigned short* Arow = A + (bm + srow) * DIM + sc;
  const unsigned short* Brow = B + (bn + srow) * DIM + sc;
  f32x4 acc[2][2] = {};

  uint4 a0 = *(const uint4*)&Arow[0];
  uint4 a1 = *(const uint4*)&Arow[8];
  uint4 b0 = *(const uint4*)&Brow[0];
  uint4 b1 = *(const uint4*)&Brow[8];
  *(uint4*)&As[0][srow * 72 + sc]     = a0;
  *(uint4*)&As[0][srow * 72 + sc + 8] = a1;
  *(uint4*)&Bs[0][srow * 72 + sc]     = b0;
  *(uint4*)&Bs[0][srow * 72 + sc + 8] = b1;
  __syncthreads();

  #pragma unroll 2
  for (int k0 = 0; k0 < DIM; k0 += 64) {
    const int cur = (k0 >> 6) & 1;
    const bool more = (k0 + 64 < DIM);
    if (more) {
      a0 = *(const uint4*)&Arow[k0 + 64];
      a1 = *(const uint4*)&Arow[k0 + 64 + 8];
      b0 = *(const uint4*)&Brow[k0 + 64];
      b1 = *(const uint4*)&Brow[k0 + 64 + 8];
    }
    #pragma unroll
    for (int ks = 0; ks < 2; ks++) {
      bf16x8 fa0 = *(const bf16x8*)&As[cur][(wr * 32 + q) * 72      + ks * 32 + g * 8];
      bf16x8 fa1 = *(const bf16x8*)&As[cur][(wr * 32 + 16 + q) * 72 + ks * 32 + g * 8];
      bf16x8 fb0 = *(const bf16x8*)&Bs[cur][(wc * 32 + q) * 72      + ks * 32 + g * 8];
      bf16x8 fb1 = *(const bf16x8*)&Bs[cur][(wc * 32 + 16 + q) * 72 + ks * 32 + g * 8];
      acc[0][0] = __builtin_amdgcn_mfma_f32_16x16x32_bf16(fa0, fb0, acc[0][0], 0, 0, 0);
      acc[0][1] = __builtin_amdgcn_mfma_f32_16x16x32_bf16(fa0, fb1, acc[0][1], 0, 0, 0);
      acc[1][0] = __builtin_amdgcn_mfma_f32_16x16x32_bf16(fa1, fb0, acc[1][0], 0, 0, 0);
      acc[1][1] = __builtin_amdgcn_mfma_f32_16x16x32_bf16(fa1, fb1, acc[1][1], 0, 0, 0);
    }
    if (more) {
      *(uint4*)&As[cur ^ 1][srow * 72 + sc]     = a0;
      *(uint4*)&As[cur ^ 1][srow * 72 + sc + 8] = a1;
      *(uint4*)&Bs[cur ^ 1][srow * 72 + sc]     = b0;
      *(uint4*)&Bs[cur ^ 1][srow * 72 + sc + 8] = b1;
      __syncthreads();
    }
  }

  #pragma unroll
  for (int i = 0; i < 2; i++) {
    #pragma unroll
    for (int j = 0; j < 2; j++) {
      const int m0 = bm + wr * 32 + i * 16 + g * 4;
      const int n  = bn + wc * 32 + j * 16 + q;
      if (z == 0) {
        float uu = u[n], vv = v[n];
        #pragma unroll
        for (int r = 0; r < 4; r++) {
          qu[(m0 + r) * DIM + n] = f2bf((acc[i][j][r] + uu) * 0.125f);
          qv[(m0 + r) * DIM + n] = f2bf((acc[i][j][r] + vv) * 0.125f);
        }
      } else if (z == 1) {
        #pragma unroll
        for (int r = 0; r < 4; r++)
          kkp[(m0 + r) * DIM + n] = f2bf(acc[i][j][r]);
      } else {
        ushort4 pk;
        pk.x = f2bf(acc[i][j][0]); pk.y = f2bf(acc[i][j][1]);
        pk.z = f2bf(acc[i][j][2]); pk.w = f2bf(acc[i][j][3]);
        *(ushort4*)&vvpT[n * SQ + m0] = pk;           // vvpT[d][t]
      }
    }
  }
}

// ---------- output GEMM: out(f32) = attout(bf16) @ Wo^T + bo ----------
__global__ __launch_bounds__(256) void gemm_out(
    const unsigned short* __restrict__ A, const unsigned short* __restrict__ B,
    float* __restrict__ out, const float* __restrict__ bo)
{
  __shared__ short As[2][64 * 72];
  __shared__ short Bs[2][64 * 72];
  const int tid = threadIdx.x;
  const int bm = blockIdx.y * 64, bn = blockIdx.x * 64;
  const int w = tid >> 6, l = tid & 63, g = l >> 4, q = l & 15;
  const int wr = w >> 1, wc = w & 1;
  const int srow = tid >> 2, sc = (tid & 3) * 16;
  const unsigned short* Arow = A + (bm + srow) * DIM + sc;
  const unsigned short* Brow = B + (bn + srow) * DIM + sc;
  f32x4 acc[2][2] = {};

  uint4 a0 = *(const uint4*)&Arow[0];
  uint4 a1 = *(const uint4*)&Arow[8];
  uint4 b0 = *(const uint4*)&Brow[0];
  uint4 b1 = *(const uint4*)&Brow[8];
  *(uint4*)&As[0][srow * 72 + sc]     = a0;
  *(uint4*)&As[0][srow * 72 + sc + 8] = a1;
  *(uint4*)&Bs[0][srow * 72 + sc]     = b0;
  *(uint4*)&Bs[0][srow * 72 + sc + 8] = b1;
  __syncthreads();

  #pragma unroll 2
  for (int k0 = 0; k0 < DIM; k0 += 64) {
    const int cur = (k0 >> 6) & 1;
    const bool more = (k0 + 64 < DIM);
    if (more) {
      a0 = *(const uint4*)&Arow[k0 + 64];
      a1 = *(const uint4*)&Arow[k0 + 64 + 8];
      b0 = *(const uint4*)&Brow[k0 + 64];
      b1 = *(const uint4*)&Brow[k0 + 64 + 8];
    }
    #pragma unroll
    for (int ks = 0; ks < 2; ks++) {
      bf16x8 fa0 = *(const bf16x8*)&As[cur][(wr * 32 + q) * 72      + ks * 32 + g * 8];
      bf16x8 fa1 = *(const bf16x8*)&As[cur][(wr * 32 + 16 + q) * 72 + ks * 32 + g * 8];
      bf16x8 fb0 = *(const bf16x8*)&Bs[cur][(wc * 32 + q) * 72      + ks * 32 + g * 8];
      bf16x8 fb1 = *(const bf16x8*)&Bs[cur][(wc * 32 + 16 + q) * 72 + ks * 32 + g * 8];
      acc[0][0] = __builtin_amdgcn_mfma_f32_16x16x32_bf16(fa0, fb0, acc[0][0], 0, 0, 0);
      acc[0][1] = __builtin_amdgcn_mfma_f32_16x16x32_bf16(fa0, fb1, acc[0][1], 0, 0, 0);
      acc[1][0] = __builtin_amdgcn_mfma_f32_16x16x32_bf16(fa1, fb0, acc[1][0], 0, 0, 0);
      acc[1][1] = __builtin_amdgcn_mfma_f32_16x16x32_bf16(fa1, fb1, acc[1][1], 0, 0, 0);
    }
    if (more) {
      *(uint4*)&As[cur ^ 1][srow * 72 + sc]     = a0;
      *(uint4*)&As[cur ^ 1][srow * 72 + sc + 8] = a1;
      *(uint4*)&Bs[cur ^ 1][srow * 72 + sc]     = b0;
      *(uint4*)&Bs[cur ^ 1][srow * 72 + sc + 8] = b1;
      __syncthreads();
    }
  }

  #pragma unroll
  for (int i = 0; i < 2; i++) {
    #pragma unroll
    for (int j = 0; j < 2; j++) {
      const int m0 = bm + wr * 32 + i * 16 + g * 4;
      const int n  = bn + wc * 32 + j * 16 + q;
      float bb = bo[n];
      #pragma unroll
      for (int r = 0; r < 4; r++)
        out[(m0 + r) * DIM + n] = acc[i][j][r] + bb;
    }
  }
}

// ---------- fused MFMA flash attention, split-t + reg-prefetch staging ----------
__global__ __launch_bounds__(256) void attn_mfma(
    const unsigned short* __restrict__ qu, const unsigned short* __restrict__ qv,
    const unsigned short* __restrict__ kkp, const unsigned short* __restrict__ vvpT,
    const unsigned short* __restrict__ Rc, float* __restrict__ PO,
    float* __restrict__ ML)
{
  __shared__ short Ks[64 * 72];     // K tile  [t][d]
  __shared__ short Vs[64 * 72];     // V^T tile [d][t]
  __shared__ short Rcs[128 * 72];   // Rc band [p][d]
  __shared__ short Ps[64 * 72];     // P  [s][t]
  __shared__ float Gs[64 * 84];     // G  [s][p_rel]

  const int tid = threadIdx.x;
  const int h  = blockIdx.x >> 4;
  const int s0 = (blockIdx.x & 15) * 64;
  const int th = blockIdx.y;
  const int w = tid >> 6, l = tid & 63, g = l >> 4, q = l & 15;
  const int col0 = h * HDIM;

  const int sw = s0 + w * 16 + q;
  bf16x8 qub[2], qvb[2];
  qub[0] = *(const bf16x8*)&qu[sw * DIM + col0 + g * 8];
  qub[1] = *(const bf16x8*)&qu[sw * DIM + col0 + 32 + g * 8];
  qvb[0] = *(const bf16x8*)&qv[sw * DIM + col0 + g * 8];
  qvb[1] = *(const bf16x8*)&qv[sw * DIM + col0 + 32 + g * 8];

  f32x4 accO[4] = {};
  float m_run = -1e30f, l_run = 0.f;

  const int srow = tid >> 2, sc = (tid & 3) * 16;
  const int rrow = tid >> 1, rc = (tid & 1) * 32;

  const int tstart = th * 512, tend = th * 512 + 512;

  uint4 kr0, kr1, vr0, vr1, rr0, rr1, rr2, rr3;
  // prologue: load first tile
  {
    const int t0 = tstart;
    kr0 = *(const uint4*)&kkp[(t0 + srow) * DIM + col0 + sc];
    kr1 = *(const uint4*)&kkp[(t0 + srow) * DIM + col0 + sc + 8];
    vr0 = *(const uint4*)&vvpT[(col0 + srow) * SQ + t0 + sc];
    vr1 = *(const uint4*)&vvpT[(col0 + srow) * SQ + t0 + sc + 8];
    const int P0 = s0 - t0 + 960;
    rr0 = *(const uint4*)&Rc[(P0 + rrow) * HDIM + rc];
    rr1 = *(const uint4*)&Rc[(P0 + rrow) * HDIM + rc + 8];
    rr2 = *(const uint4*)&Rc[(P0 + rrow) * HDIM + rc + 16];
    rr3 = *(const uint4*)&Rc[(P0 + rrow) * HDIM + rc + 24];
    *(uint4*)&Ks[srow * 72 + sc]      = kr0;
    *(uint4*)&Ks[srow * 72 + sc + 8]  = kr1;
    *(uint4*)&Vs[srow * 72 + sc]      = vr0;
    *(uint4*)&Vs[srow * 72 + sc + 8]  = vr1;
    *(uint4*)&Rcs[rrow * 72 + rc]      = rr0;
    *(uint4*)&Rcs[rrow * 72 + rc + 8]  = rr1;
    *(uint4*)&Rcs[rrow * 72 + rc + 16] = rr2;
    *(uint4*)&Rcs[rrow * 72 + rc + 24] = rr3;
  }
  __syncthreads();

  for (int t0 = tstart; t0 < tend; t0 += 64) {
    const bool more = (t0 + 64 < tend);
    if (more) {
      const int tn = t0 + 64;
      kr0 = *(const uint4*)&kkp[(tn + srow) * DIM + col0 + sc];
      kr1 = *(const uint4*)&kkp[(tn + srow) * DIM + col0 + sc + 8];
      vr0 = *(const uint4*)&vvpT[(col0 + srow) * SQ + tn + sc];
      vr1 = *(const uint4*)&vvpT[(col0 + srow) * SQ + tn + sc + 8];
      const int P0 = s0 - tn + 960;
      rr0 = *(const uint4*)&Rc[(P0 + rrow) * HDIM + rc];
      rr1 = *(const uint4*)&Rc[(P0 + rrow) * HDIM + rc + 8];
      rr2 = *(const uint4*)&Rc[(P0 + rrow) * HDIM + rc + 16];
      rr3 = *(const uint4*)&Rc[(P0 + rrow) * HDIM + rc + 24];
    }

    f32x4 accS[4] = {};
    f32x4 accG[5] = {};
    #pragma unroll
    for (int ks = 0; ks < 2; ks++) {
      #pragma unroll
      for (int tf = 0; tf < 4; tf++) {
        bf16x8 a = *(const bf16x8*)&Ks[(tf * 16 + q) * 72 + ks * 32 + g * 8];
        accS[tf] = __builtin_amdgcn_mfma_f32_16x16x32_bf16(a, qub[ks], accS[tf], 0, 0, 0);
      }
      #pragma unroll
      for (int pf = 0; pf < 5; pf++) {
        bf16x8 a = *(const bf16x8*)&Rcs[(w * 16 + pf * 16 + q) * 72 + ks * 32 + g * 8];
        accG[pf] = __builtin_amdgcn_mfma_f32_16x16x32_bf16(a, qvb[ks], accG[pf], 0, 0, 0);
      }
    }
    #pragma unroll
    for (int pf = 0; pf < 5; pf++)
      *(f32x4*)&Gs[(w * 16 + q) * 84 + pf * 16 + g * 4] = accG[pf];

    float pvals[16];
    float mx = -1e30f;
    #pragma unroll
    for (int tf = 0; tf < 4; tf++) {
      #pragma unroll
      for (int r = 0; r < 4; r++) {
        int t_rel = tf * 16 + g * 4 + r;
        float sval = accS[tf][r] + Gs[(w * 16 + q) * 84 + (q - t_rel + 63)];
        pvals[tf * 4 + r] = sval;
        mx = fmaxf(mx, sval);
      }
    }
    mx = fmaxf(mx, __shfl_xor(mx, 16));
    mx = fmaxf(mx, __shfl_xor(mx, 32));
    float m_new = fmaxf(m_run, mx);
    float scale = __expf(m_run - m_new);
    float rsum = 0.f;
    #pragma unroll
    for (int i = 0; i < 16; i++) {
      float p = __expf(pvals[i] - m_new);
      pvals[i] = p;
      rsum += p;
    }
    rsum += __shfl_xor(rsum, 16);
    rsum += __shfl_xor(rsum, 32);
    l_run = l_run * scale + rsum;
    m_run = m_new;
    #pragma unroll
    for (int df = 0; df < 4; df++) {
      #pragma unroll
      for (int r = 0; r < 4; r++) accO[df][r] *= scale;
    }
    #pragma unroll
    for (int tf = 0; tf < 4; tf++) {
      unsigned int lo = pkbf(pvals[tf * 4 + 0], pvals[tf * 4 + 1]);
      unsigned int hi = pkbf(pvals[tf * 4 + 2], pvals[tf * 4 + 3]);
      *(uint2*)&Ps[(w * 16 + q) * 72 + tf * 16 + g * 4] = make_uint2(lo, hi);
    }
    #pragma unroll
    for (int ks = 0; ks < 2; ks++) {
      bf16x8 b = *(const bf16x8*)&Ps[(w * 16 + q) * 72 + ks * 32 + g * 8];
      #pragma unroll
      for (int df = 0; df < 4; df++) {
        bf16x8 a = *(const bf16x8*)&Vs[(df * 16 + q) * 72 + ks * 32 + g * 8];
        accO[df] = __builtin_amdgcn_mfma_f32_16x16x32_bf16(a, b, accO[df], 0, 0, 0);
      }
    }

    if (more) {
      __syncthreads();   // all waves done reading Ks/Vs/Rcs
      *(uint4*)&Ks[srow * 72 + sc]      = kr0;
      *(uint4*)&Ks[srow * 72 + sc + 8]  = kr1;
      *(uint4*)&Vs[srow * 72 + sc]      = vr0;
      *(uint4*)&Vs[srow * 72 + sc + 8]  = vr1;
      *(uint4*)&Rcs[rrow * 72 + rc]      = rr0;
      *(uint4*)&Rcs[rrow * 72 + rc + 8]  = rr1;
      *(uint4*)&Rcs[rrow * 72 + rc + 16] = rr2;
      *(uint4*)&Rcs[rrow * 72 + rc + 24] = rr3;
      __syncthreads();   // tile ready
    }
  }

  // partial store: PO[tile][s_local][d] (f32), ML[tile][s_local][{m,l}]
  const int tile = blockIdx.x * 2 + th;
  float* POt = PO + (size_t)tile * 4096;
  const int sl = w * 16 + q;
  #pragma unroll
  for (int df = 0; df < 4; df++)
    *(f32x4*)&POt[sl * 64 + df * 16 + g * 4] = accO[df];
  if (g == 0) {
    ML[tile * 128 + sl * 2]     = m_run;
    ML[tile * 128 + sl * 2 + 1] = l_run;
  }
}

// ---------- combine two t-half partials -> attout (bf16) ----------
__global__ __launch_bounds__(256) void attn_combine(
    const float* __restrict__ PO, const float* __restrict__ ML,
    unsigned short* __restrict__ attout)
{
  int gid = blockIdx.x * 256 + threadIdx.x;   // 262144
  int s  = gid >> 8;                          // 0..1023
  int c  = (gid & 255) * 4;                   // column group (h*64 + d)
  int h  = c >> 6;
  int sb = s >> 6, sl = s & 63;
  int tA = (h * 16 + sb) * 2, tB = tA + 1;
  float mA = ML[tA * 128 + sl * 2], lA = ML[tA * 128 + sl * 2 + 1];
  float mB = ML[tB * 128 + sl * 2], lB = ML[tB * 128 + sl * 2 + 1];
  float m = fmaxf(mA, mB);
  float wA = __expf(mA - m), wB = __expf(mB - m);
  float inv = 1.f / (lA * wA + lB * wB);
  wA *= inv; wB *= inv;
  int dl = c & 63;
  float4 a = *(const float4*)&PO[(size_t)tA * 4096 + sl * 64 + dl];
  float4 b = *(const float4*)&PO[(size_t)tB * 4096 + sl * 64 + dl];
  uint2 o;
  o.x = pkbf(a.x * wA + b.x * wB, a.y * wA + b.y * wB);
  o.y = pkbf(a.z * wA + b.z * wB, a.w * wA + b.w * wB);
  *(uint2*)&attout[s * DIM + c] = o;
}

extern "C" void kernel_launch(void* const* d_in, const int* in_sizes, int n_in,
                              void* d_out, int out_size, void* d_ws, size_t ws_size,
                              hipStream_t stream) {
  const float* value = (const float*)d_in[0];
  const float* key   = (const float*)d_in[1];
  const float* query = (const float*)d_in[2];
  const float* Wq    = (const float*)d_in[3];
  const float* Wk    = (const float*)d_in[4];
  const float* Wv    = (const float*)d_in[5];
  const float* u     = (const float*)d_in[6];
  const float* v     = (const float*)d_in[7];
  const float* Wo    = (const float*)d_in[8];
  const float* bo    = (const float*)d_in[9];
  float* out = (float*)d_out;

  unsigned short* ws = (unsigned short*)d_ws;
  unsigned short* bfin   = ws;                       // 7 x 1M bf16: q,k,v,Wq,Wk,Wv,Wo
  unsigned short* qu_p   = bfin   + 7 * (1 << 20);
  unsigned short* qv_p   = qu_p   + (1 << 20);
  unsigned short* kkp    = qv_p   + (1 << 20);
  unsigned short* vvpT   = kkp    + (1 << 20);
  unsigned short* attout = vvpT   + (1 << 20);
  unsigned short* Rc     = attout + (1 << 20);       // 2048*64
  float* PO = (float*)(Rc + 2048 * 64);              // 512 tiles x 64 x 64 f32
  float* ML = PO + (size_t)512 * 4096;               // 512 x 64 x 2 f32

  prep_kernel<<<3840, 256, 0, stream>>>(query, key, value, Wq, Wk, Wv, Wo, bfin, Rc);

  dim3 gqkv(16, 16, 3);
  gemm_qkv<<<gqkv, 256, 0, stream>>>(bfin, qu_p, qv_p, kkp, vvpT, u, v);

  dim3 gattn(NH * (SQ / 64), 2);
  attn_mfma<<<gattn, 256, 0, stream>>>(qu_p, qv_p, kkp, vvpT, Rc, PO, ML);
  attn_combine<<<1024, 256, 0, stream>>>(PO, ML, attout);

  dim3 gg(16, 16);
  gemm_out<<<gg, 256, 0, stream>>>(attout, bfin + 6 * (1 << 20), out, bo);
}